// Round 15
// baseline (64.131 us; speedup 1.0000x reference)
//
#include <hip/hip_runtime.h>
#include <hip/hip_bf16.h>
#include <math.h>

namespace {

constexpr int B = 4, S = 2048, D = 1024, H = 64, NH = 16;
constexpr int BS = B * S;                  // 8192 rows
constexpr float SCALE2 = 0.125f * 1.4426950408889634f;  // 1/sqrt(H)*log2(e): exp2 domain
constexpr float M0 = 8.0f;                 // fixed softmax shift (exact; range-safe)

constexpr int AUNITS_PB = 272;             // sum_{J=0..31} ceil((J+1)/2)
constexpr int AUNITS = AUNITS_PB * 4;      // 1088

using f32x4 = __attribute__((ext_vector_type(4))) float;
using short8b = __attribute__((ext_vector_type(8))) short;  // 8 bf16 (4 VGPRs)

__device__ inline ushort f2bf(float f) {
    __hip_bfloat16 h = __float2bfloat16(f);
    return *reinterpret_cast<ushort*>(&h);
}
__device__ inline float bf2f(ushort u) {
    __hip_bfloat16 h = *reinterpret_cast<__hip_bfloat16*>(&u);
    return __bfloat162float(h);
}
// units preceding 64-row group J (chunks of <=2 k-tiles, per batch)
__device__ inline int cum_units(int J) {
    return (J & 1) ? ((J + 1) * (J + 1) / 4) : (J * J / 4 + J / 2);
}

// ---------------------------------------------------------------------------
// prep: [bid<768]  Wt[n][k] bf16 = W{q,k,v}[k][n&63]   (QKV B-operand)
//       [bid>=768] Wpet[e][h] bf16 = sum_t Wproj[t*64+h][e]  (proj B-operand)
// ---------------------------------------------------------------------------
__global__ __launch_bounds__(256) void prep_kernel(const float* __restrict__ Wq,
                                                   const float* __restrict__ Wk,
                                                   const float* __restrict__ Wv,
                                                   const float* __restrict__ Wproj,
                                                   ushort* __restrict__ Wt,
                                                   ushort* __restrict__ Wpet) {
    const int bid = blockIdx.x;
    const int tid = threadIdx.x;
    if (bid < 768) {
        const int idx = bid * 256 + tid;          // 0..196607
        const int n = idx >> 10, k = idx & 1023;
        const float* __restrict__ W = (n < 64) ? Wq : (n < 128) ? Wk : Wv;
        Wt[idx] = f2bf(W[k * 64 + (n & 63)]);
    } else {
        const int idx = (bid - 768) * 256 + tid;  // 0..65535
        const int e = idx & 1023, h = idx >> 10;
        float s = 0.f;
#pragma unroll
        for (int t = 0; t < NH; ++t) s += Wproj[(t * H + h) * D + e];
        Wpet[e * 64 + h] = f2bf(s);
    }
}

// ---------------------------------------------------------------------------
// qkv via MFMA, TLP version (round-12, unchanged): M-tile 16, grid 512
// (2 blocks/CU), K-step 128.  T_qkv6 = 14.1 us (round-13 measurement).
// ---------------------------------------------------------------------------
__global__ __launch_bounds__(256) void qkv6_kernel(const float* __restrict__ x,
                                                   const ushort* __restrict__ Wt,
                                                   ushort* __restrict__ qb,
                                                   ushort* __restrict__ kb,
                                                   ushort* __restrict__ vb) {
    __shared__ ushort xs[16 * 128];
    __shared__ ushort wsm[192 * 128];
    const int tid = threadIdx.x;
    const int lane = tid & 63;
    const int li = lane & 15, lg = lane >> 4;
    const int wn = tid >> 6;               // wave = N-group (48 cols)
    const int row0 = blockIdx.x * 16;

    f32x4 acc[3];
#pragma unroll
    for (int t = 0; t < 3; ++t) acc[t] = (f32x4){0.f, 0.f, 0.f, 0.f};

    const int xrow = tid >> 4;             // 0..15
    const int xc4 = (tid & 15) * 4;        // 0..60

    const char* xsb = reinterpret_cast<const char*>(xs);
    const char* wsb = reinterpret_cast<const char*>(wsm);

    for (int k0 = 0; k0 < 1024; k0 += 128) {
        __syncthreads();
        // ---- stage x (fp32->bf16), two 64-col halves, 256B-coalesced ----
#pragma unroll
        for (int hh = 0; hh < 2; ++hh) {
            const float4 f = *reinterpret_cast<const float4*>(
                x + (size_t)(row0 + xrow) * 1024 + k0 + hh * 64 + xc4);
            ushort u[4] = {f2bf(f.x), f2bf(f.y), f2bf(f.z), f2bf(f.w)};
            int boff = xrow * 256 + (hh * 64 + xc4) * 2;
            boff ^= (xrow & 7) << 4;
            *reinterpret_cast<uint2*>(const_cast<char*>(xsb) + boff) =
                *reinterpret_cast<uint2*>(u);
        }
        // ---- stage W^T tile [192][128] bf16: 12 int4/thread ----
#pragma unroll
        for (int it = 0; it < 12; ++it) {
            const int cid = tid + it * 256;        // 0..3071
            const int n = cid >> 4, kc = cid & 15;
            const int4 val = *reinterpret_cast<const int4*>(
                Wt + (size_t)n * 1024 + k0 + kc * 8);
            int boff = n * 256 + kc * 16;
            boff ^= (n & 7) << 4;
            *reinterpret_cast<int4*>(const_cast<char*>(wsb) + boff) = val;
        }
        __syncthreads();

        // ---- A fragments: 4 k-chunks of the wave-shared 16 rows ----
        short8b a[4];
#pragma unroll
        for (int c2 = 0; c2 < 4; ++c2) {
            int aoff = li * 256 + c2 * 64 + lg * 16;
            aoff ^= (li & 7) << 4;
            a[c2] = *reinterpret_cast<const short8b*>(xsb + aoff);
        }
#pragma unroll
        for (int t = 0; t < 3; ++t) {
            const int n = wn * 48 + t * 16 + li;
            const int swz = (n & 7) << 4;
#pragma unroll
            for (int c2 = 0; c2 < 4; ++c2) {
                int boff = (n * 256 + c2 * 64 + lg * 16) ^ swz;
                const short8b bfrag = *reinterpret_cast<const short8b*>(wsb + boff);
                acc[t] = __builtin_amdgcn_mfma_f32_16x16x32_bf16(a[c2], bfrag, acc[t], 0, 0, 0);
            }
        }
    }

    // epilogue: C col = li (m89 layout); q scaled into exp2 domain
#pragma unroll
    for (int t = 0; t < 3; ++t) {
        const int col = wn * 48 + t * 16 + li;
        const int m = col >> 6, cc = col & 63;
        ushort* __restrict__ dst = (m == 0) ? qb : (m == 1) ? kb : vb;
        const float sc = (m == 0) ? SCALE2 : 1.f;
#pragma unroll
        for (int r = 0; r < 4; ++r) {
            const int gr = row0 + lg * 4 + r;
            dst[(size_t)gr * 64 + cc] = f2bf(acc[t][r] * sc);
        }
    }
}

// ---------------------------------------------------------------------------
// MFMA causal flash attention v4 (round-14, unchanged). Idempotent: pure
// function of qb/kb/vb -> po/pl. Launched TWICE this round purely to measure
// T_attn4 = dur_us - 53.47.
// ---------------------------------------------------------------------------
__global__ __launch_bounds__(256) void attn_mfma4_kernel(const ushort* __restrict__ qb,
                                                         const ushort* __restrict__ kb16,
                                                         const ushort* __restrict__ vb16,
                                                         ushort* __restrict__ po,
                                                         float* __restrict__ pl) {
    __shared__ ushort ksm[128 * 64];       // 16 KB, swizzled rows of 128B
    __shared__ ushort vtm[64 * 128];       // 16 KB, swizzled rows of 256B
    __shared__ ushort plds[4][2][16 * 72]; // 18 KB, per-wave double-buffered P

    const int tid = threadIdx.x;
    const int lane = tid & 63;
    const int wave = tid >> 6;
    const int li = lane & 15, lg = lane >> 4;
    const int u = blockIdx.x;
    const int b = u & 3;
    const int ub = u >> 2;                 // 0..271

    // decode ub -> (J, c)
    int J = (int)(2.f * sqrtf((float)ub + 0.5f));
    if (J > 31) J = 31;
    while (cum_units(J + 1) <= ub) ++J;
    while (cum_units(J) > ub) --J;
    const int c = ub - cum_units(J);
    const int key0 = c * 128;

    // Q fragments: wave's 16 rows
    const ushort* qg = qb + (size_t)(b * S + J * 64 + wave * 16 + li) * 64 + lg * 8;
    const short8b aq0 = *reinterpret_cast<const short8b*>(qg);
    const short8b aq1 = *reinterpret_cast<const short8b*>(qg + 32);

    short8b bones;
#pragma unroll
    for (int i = 0; i < 8; ++i) bones[i] = (short)0x3F80;   // bf16 1.0

    // ---- stage K tile: 128 keys x 64 h, 4 int4/thread ----
    {
        const ushort* kg = kb16 + (size_t)(b * S + key0) * 64;
#pragma unroll
        for (int it = 0; it < 4; ++it) {
            const int f = tid + it * 256;      // 16B chunk id 0..1023
            const int key = f >> 3, hd8 = f & 7;
            const int4 val = *reinterpret_cast<const int4*>(kg + key * 64 + hd8 * 8);
            int byteoff = (key << 7) + (hd8 << 4);
            byteoff ^= (key & 7) << 4;
            *reinterpret_cast<int4*>(reinterpret_cast<char*>(ksm) + byteoff) = val;
        }
    }
    // ---- stage V^T tile: [64 h][128 keys], 2 items/thread ----
    {
        const ushort* vg = vb16 + (size_t)(b * S + key0) * 64;
#pragma unroll
        for (int it = 0; it < 2; ++it) {
            const int item = tid + it * 256;   // 0..511
            const int kk = item >> 4;          // key quad 0..31
            const int hq = item & 15;          // h quad
            const uint2 a0 = *reinterpret_cast<const uint2*>(vg + (kk * 4 + 0) * 64 + hq * 4);
            const uint2 a1 = *reinterpret_cast<const uint2*>(vg + (kk * 4 + 1) * 64 + hq * 4);
            const uint2 a2 = *reinterpret_cast<const uint2*>(vg + (kk * 4 + 2) * 64 + hq * 4);
            const uint2 a3 = *reinterpret_cast<const uint2*>(vg + (kk * 4 + 3) * 64 + hq * 4);
#pragma unroll
            for (int i = 0; i < 4; ++i) {
                const uint s0 = (i < 2) ? a0.x : a0.y;
                const uint s1 = (i < 2) ? a1.x : a1.y;
                const uint s2 = (i < 2) ? a2.x : a2.y;
                const uint s3 = (i < 2) ? a3.x : a3.y;
                const uint sel = (i & 1) ? 0x07060302u : 0x05040100u;
                const uint w0 = __builtin_amdgcn_perm(s1, s0, sel);
                const uint w1 = __builtin_amdgcn_perm(s3, s2, sel);
                const int h = hq * 4 + i;
                int byteoff = (h << 8) + (kk << 3);
                byteoff ^= (h & 7) << 4;
                *reinterpret_cast<uint2*>(reinterpret_cast<char*>(vtm) + byteoff) =
                    make_uint2(w0, w1);
            }
        }
    }
    __syncthreads();   // the ONLY block barrier

    // ---- QK^T: 8 key-subtiles x 2 k-chunks ----
    f32x4 accs[8];
#pragma unroll
    for (int t = 0; t < 8; ++t) accs[t] = (f32x4){0.f, 0.f, 0.f, 0.f};
#pragma unroll
    for (int t = 0; t < 8; ++t) {
        const int key = t * 16 + li;
#pragma unroll
        for (int c2 = 0; c2 < 2; ++c2) {
            int byteoff = (key << 7) + (c2 << 6) + (lg << 4);
            byteoff ^= (key & 7) << 4;
            const short8b bk = *reinterpret_cast<const short8b*>(
                reinterpret_cast<const char*>(ksm) + byteoff);
            accs[t] = __builtin_amdgcn_mfma_f32_16x16x32_bf16(
                (c2 == 0) ? aq0 : aq1, bk, accs[t], 0, 0, 0);
        }
    }

    f32x4 oacc[4];
#pragma unroll
    for (int t = 0; t < 4; ++t) oacc[t] = (f32x4){0.f, 0.f, 0.f, 0.f};
    f32x4 lacc = (f32x4){0.f, 0.f, 0.f, 0.f};

#pragma unroll
    for (int half = 0; half < 2; ++half) {
        // ---- softmax + unconditional causal mask -> P half in LDS ----
#pragma unroll
        for (int tt = 0; tt < 4; ++tt) {
            const int t = half * 4 + tt;
            const int key = key0 + t * 16 + li;
#pragma unroll
            for (int r = 0; r < 4; ++r) {
                const int qrow = J * 64 + wave * 16 + lg * 4 + r;
                const float s = (key > qrow) ? -1e30f : accs[t][r];
                plds[wave][half][(lg * 4 + r) * 72 + tt * 16 + li] = f2bf(exp2f(s - M0));
            }
        }

        // ---- PV + row-sums (same-wave plds read: lgkmcnt suffices) ----
        const char* pb = reinterpret_cast<const char*>(plds[wave][half]);
        const short8b ap0 = *reinterpret_cast<const short8b*>(pb + li * 144 + (lg << 4));
        const short8b ap1 = *reinterpret_cast<const short8b*>(pb + li * 144 + 64 + (lg << 4));
#pragma unroll
        for (int t = 0; t < 4; ++t) {
            const int h = t * 16 + li;
#pragma unroll
            for (int c2 = 0; c2 < 2; ++c2) {
                int byteoff = (h << 8) + (half << 7) + (c2 << 6) + (lg << 4);
                byteoff ^= (h & 7) << 4;
                const short8b bv = *reinterpret_cast<const short8b*>(
                    reinterpret_cast<const char*>(vtm) + byteoff);
                oacc[t] = __builtin_amdgcn_mfma_f32_16x16x32_bf16(
                    (c2 == 0) ? ap0 : ap1, bv, oacc[t], 0, 0, 0);
            }
        }
        lacc = __builtin_amdgcn_mfma_f32_16x16x32_bf16(ap0, bones, lacc, 0, 0, 0);
        lacc = __builtin_amdgcn_mfma_f32_16x16x32_bf16(ap1, bones, lacc, 0, 0, 0);
    }

    // ---- write partials (unnormalized O and row-sums l) ----
    if (li == 0) {
#pragma unroll
        for (int r = 0; r < 4; ++r)
            pl[u * 64 + wave * 16 + lg * 4 + r] = lacc[r];
    }
#pragma unroll
    for (int t = 0; t < 4; ++t)
#pragma unroll
        for (int r = 0; r < 4; ++r)
            po[(size_t)u * 4096 + (wave * 16 + lg * 4 + r) * 64 + t * 16 + li] =
                f2bf(oacc[t][r]);
}

// ---------------------------------------------------------------------------
// Fused combine + projection (round-12, unchanged).
// ---------------------------------------------------------------------------
__global__ __launch_bounds__(256) void proj_fused_kernel(const ushort* __restrict__ po,
                                                         const float* __restrict__ pl,
                                                         const ushort* __restrict__ Wpet,
                                                         const float* __restrict__ bias,
                                                         float* __restrict__ out) {
    __shared__ ushort ctxs[16 * 64];
    const int tid = threadIdx.x;
    const int bid = blockIdx.x;            // 0..511
    const int b = bid >> 7, j = bid & 127;
    const int J = j >> 2;
    const int nc = (J + 2) >> 1;
    const int cumJ = cum_units(J);

    // ---- phase 1: combine partials; thread -> (row qr, 4 h's) ----
    {
        const int qr = tid >> 4, hq = tid & 15;
        const int riu = (j & 3) * 16 + qr;     // row within 64-row unit
        float denom = 0.f;
        float acc[4] = {0.f, 0.f, 0.f, 0.f};
        for (int cc = 0; cc < nc; ++cc) {
            const int uu = (cumJ + cc) * 4 + b;
            denom += pl[uu * 64 + riu];
            const ushort* pp = po + (size_t)uu * 4096 + riu * 64 + hq * 4;
            acc[0] += bf2f(pp[0]);
            acc[1] += bf2f(pp[1]);
            acc[2] += bf2f(pp[2]);
            acc[3] += bf2f(pp[3]);
        }
        const float inv = 1.f / denom;
        ushort uu4[4] = {f2bf(acc[0] * inv), f2bf(acc[1] * inv),
                         f2bf(acc[2] * inv), f2bf(acc[3] * inv)};
        int boff = qr * 128 + hq * 8;
        boff ^= (qr & 7) << 4;
        *reinterpret_cast<uint2*>(reinterpret_cast<char*>(ctxs) + boff) =
            *reinterpret_cast<uint2*>(uu4);
    }
    __syncthreads();

    // ---- phase 2: MFMA projection ----
    const int lane = tid & 63;
    const int li = lane & 15, lg = lane >> 4;
    const int wave = tid >> 6;
    const int col0 = wave * 256;
    const int row0 = bid * 16;

    int aoff = li * 128 + lg * 16;
    aoff ^= (li & 7) << 4;
    const short8b a0 = *reinterpret_cast<const short8b*>(
        reinterpret_cast<const char*>(ctxs) + aoff);
    const short8b a1 = *reinterpret_cast<const short8b*>(
        reinterpret_cast<const char*>(ctxs) + (aoff ^ 64));

#pragma unroll
    for (int t = 0; t < 16; ++t) {
        const int col = col0 + t * 16 + li;
        const ushort* bg = Wpet + (size_t)col * 64 + lg * 8;
        const short8b b0 = *reinterpret_cast<const short8b*>(bg);
        const short8b b1 = *reinterpret_cast<const short8b*>(bg + 32);
        f32x4 acc = (f32x4){0.f, 0.f, 0.f, 0.f};
        acc = __builtin_amdgcn_mfma_f32_16x16x32_bf16(a0, b0, acc, 0, 0, 0);
        acc = __builtin_amdgcn_mfma_f32_16x16x32_bf16(a1, b1, acc, 0, 0, 0);
        const float bb = bias[col];
#pragma unroll
        for (int r = 0; r < 4; ++r)
            out[(size_t)(row0 + lg * 4 + r) * 1024 + col] = acc[r] + bb;
    }
}

}  // namespace

extern "C" void kernel_launch(void* const* d_in, const int* in_sizes, int n_in,
                              void* d_out, int out_size, void* d_ws, size_t ws_size,
                              hipStream_t stream) {
    const float* x     = (const float*)d_in[0];
    const float* Wq    = (const float*)d_in[1];
    const float* Wk    = (const float*)d_in[2];
    const float* Wv    = (const float*)d_in[3];
    const float* Wproj = (const float*)d_in[4];
    const float* bproj = (const float*)d_in[5];
    float* out = (float*)d_out;

    const size_t BSH = (size_t)BS * H;          // 524288
    ushort* qb   = (ushort*)d_ws;
    ushort* kb   = qb + BSH;
    ushort* vb   = kb + BSH;
    ushort* Wt   = vb + BSH;                    // 192*1024
    ushort* Wpet = Wt + 192 * 1024;             // 1024*64
    ushort* po   = Wpet + 65536;                // AUNITS*4096
    float*  pl   = (float*)(po + (size_t)AUNITS * 4096);

    hipLaunchKernelGGL(prep_kernel, dim3(1024), dim3(256), 0, stream, Wq, Wk, Wv, Wproj, Wt, Wpet);
    hipLaunchKernelGGL(qkv6_kernel, dim3(BS / 16), dim3(256), 0, stream, x, Wt, qb, kb, vb);
    // MEASUREMENT: attn4 launched twice (idempotent). dur_us - 53.47 ~= T_attn4.
    hipLaunchKernelGGL(attn_mfma4_kernel, dim3(AUNITS), dim3(256), 0, stream,
                       qb, kb, vb, po, pl);
    hipLaunchKernelGGL(attn_mfma4_kernel, dim3(AUNITS), dim3(256), 0, stream,
                       qb, kb, vb, po, pl);
    hipLaunchKernelGGL(proj_fused_kernel, dim3(512), dim3(256), 0, stream,
                       po, pl, Wpet, bproj, out);
}

// Round 16
// 50.152 us; speedup vs baseline: 1.2787x; 1.2787x over previous
//
#include <hip/hip_runtime.h>
#include <hip/hip_bf16.h>
#include <math.h>

namespace {

constexpr int B = 4, S = 2048, D = 1024, H = 64, NH = 16;
constexpr int BS = B * S;                  // 8192 rows
constexpr float SCALE2 = 0.125f * 1.4426950408889634f;  // 1/sqrt(H)*log2(e): exp2 domain
constexpr float M0 = 8.0f;                 // fixed softmax shift (exact; range-safe)

constexpr int AUNITS_PB = 272;             // sum_{J=0..31} ceil((J+1)/2)
constexpr int AUNITS = AUNITS_PB * 4;      // 1088

using f32x4 = __attribute__((ext_vector_type(4))) float;
using short8b = __attribute__((ext_vector_type(8))) short;  // 8 bf16 (4 VGPRs)

__device__ inline ushort f2bf(float f) {
    __hip_bfloat16 h = __float2bfloat16(f);
    return *reinterpret_cast<ushort*>(&h);
}
__device__ inline float bf2f(ushort u) {
    __hip_bfloat16 h = *reinterpret_cast<__hip_bfloat16*>(&u);
    return __bfloat162float(h);
}
// units preceding 64-row group J (chunks of <=2 k-tiles, per batch)
__device__ inline int cum_units(int J) {
    return (J & 1) ? ((J + 1) * (J + 1) / 4) : (J * J / 4 + J / 2);
}

// ---------------------------------------------------------------------------
// prep: [bid<768]  Wt[n][k] bf16 = W{q,k,v}[k][n&63]   (QKV B-operand)
//       [bid>=768] Wpet[e][h] bf16 = sum_t Wproj[t*64+h][e]  (proj B-operand)
// ---------------------------------------------------------------------------
__global__ __launch_bounds__(256) void prep_kernel(const float* __restrict__ Wq,
                                                   const float* __restrict__ Wk,
                                                   const float* __restrict__ Wv,
                                                   const float* __restrict__ Wproj,
                                                   ushort* __restrict__ Wt,
                                                   ushort* __restrict__ Wpet) {
    const int bid = blockIdx.x;
    const int tid = threadIdx.x;
    if (bid < 768) {
        const int idx = bid * 256 + tid;          // 0..196607
        const int n = idx >> 10, k = idx & 1023;
        const float* __restrict__ W = (n < 64) ? Wq : (n < 128) ? Wk : Wv;
        Wt[idx] = f2bf(W[k * 64 + (n & 63)]);
    } else {
        const int idx = (bid - 768) * 256 + tid;  // 0..65535
        const int e = idx & 1023, h = idx >> 10;
        float s = 0.f;
#pragma unroll
        for (int t = 0; t < NH; ++t) s += Wproj[(t * H + h) * D + e];
        Wpet[e * 64 + h] = f2bf(s);
    }
}

// ---------------------------------------------------------------------------
// qkv via MFMA, TLP version (round-12, unchanged): M-tile 16, grid 512
// (2 blocks/CU), K-step 128.  T_qkv6 = 14.1 us (round-13 measurement).
// ---------------------------------------------------------------------------
__global__ __launch_bounds__(256) void qkv6_kernel(const float* __restrict__ x,
                                                   const ushort* __restrict__ Wt,
                                                   ushort* __restrict__ qb,
                                                   ushort* __restrict__ kb,
                                                   ushort* __restrict__ vb) {
    __shared__ ushort xs[16 * 128];
    __shared__ ushort wsm[192 * 128];
    const int tid = threadIdx.x;
    const int lane = tid & 63;
    const int li = lane & 15, lg = lane >> 4;
    const int wn = tid >> 6;               // wave = N-group (48 cols)
    const int row0 = blockIdx.x * 16;

    f32x4 acc[3];
#pragma unroll
    for (int t = 0; t < 3; ++t) acc[t] = (f32x4){0.f, 0.f, 0.f, 0.f};

    const int xrow = tid >> 4;             // 0..15
    const int xc4 = (tid & 15) * 4;        // 0..60

    const char* xsb = reinterpret_cast<const char*>(xs);
    const char* wsb = reinterpret_cast<const char*>(wsm);

    for (int k0 = 0; k0 < 1024; k0 += 128) {
        __syncthreads();
        // ---- stage x (fp32->bf16), two 64-col halves, 256B-coalesced ----
#pragma unroll
        for (int hh = 0; hh < 2; ++hh) {
            const float4 f = *reinterpret_cast<const float4*>(
                x + (size_t)(row0 + xrow) * 1024 + k0 + hh * 64 + xc4);
            ushort u[4] = {f2bf(f.x), f2bf(f.y), f2bf(f.z), f2bf(f.w)};
            int boff = xrow * 256 + (hh * 64 + xc4) * 2;
            boff ^= (xrow & 7) << 4;
            *reinterpret_cast<uint2*>(const_cast<char*>(xsb) + boff) =
                *reinterpret_cast<uint2*>(u);
        }
        // ---- stage W^T tile [192][128] bf16: 12 int4/thread ----
#pragma unroll
        for (int it = 0; it < 12; ++it) {
            const int cid = tid + it * 256;        // 0..3071
            const int n = cid >> 4, kc = cid & 15;
            const int4 val = *reinterpret_cast<const int4*>(
                Wt + (size_t)n * 1024 + k0 + kc * 8);
            int boff = n * 256 + kc * 16;
            boff ^= (n & 7) << 4;
            *reinterpret_cast<int4*>(const_cast<char*>(wsb) + boff) = val;
        }
        __syncthreads();

        // ---- A fragments: 4 k-chunks of the wave-shared 16 rows ----
        short8b a[4];
#pragma unroll
        for (int c2 = 0; c2 < 4; ++c2) {
            int aoff = li * 256 + c2 * 64 + lg * 16;
            aoff ^= (li & 7) << 4;
            a[c2] = *reinterpret_cast<const short8b*>(xsb + aoff);
        }
#pragma unroll
        for (int t = 0; t < 3; ++t) {
            const int n = wn * 48 + t * 16 + li;
            const int swz = (n & 7) << 4;
#pragma unroll
            for (int c2 = 0; c2 < 4; ++c2) {
                int boff = (n * 256 + c2 * 64 + lg * 16) ^ swz;
                const short8b bfrag = *reinterpret_cast<const short8b*>(wsb + boff);
                acc[t] = __builtin_amdgcn_mfma_f32_16x16x32_bf16(a[c2], bfrag, acc[t], 0, 0, 0);
            }
        }
    }

    // epilogue: C col = li (m89 layout); q scaled into exp2 domain
#pragma unroll
    for (int t = 0; t < 3; ++t) {
        const int col = wn * 48 + t * 16 + li;
        const int m = col >> 6, cc = col & 63;
        ushort* __restrict__ dst = (m == 0) ? qb : (m == 1) ? kb : vb;
        const float sc = (m == 0) ? SCALE2 : 1.f;
#pragma unroll
        for (int r = 0; r < 4; ++r) {
            const int gr = row0 + lg * 4 + r;
            dst[(size_t)gr * 64 + cc] = f2bf(acc[t][r] * sc);
        }
    }
}

// ---------------------------------------------------------------------------
// MFMA causal flash attention v4 (round-14, unchanged).
// T_attn4 = 10.7 us (round-15 measurement).
// ---------------------------------------------------------------------------
__global__ __launch_bounds__(256) void attn_mfma4_kernel(const ushort* __restrict__ qb,
                                                         const ushort* __restrict__ kb16,
                                                         const ushort* __restrict__ vb16,
                                                         ushort* __restrict__ po,
                                                         float* __restrict__ pl) {
    __shared__ ushort ksm[128 * 64];       // 16 KB, swizzled rows of 128B
    __shared__ ushort vtm[64 * 128];       // 16 KB, swizzled rows of 256B
    __shared__ ushort plds[4][2][16 * 72]; // 18 KB, per-wave double-buffered P

    const int tid = threadIdx.x;
    const int lane = tid & 63;
    const int wave = tid >> 6;
    const int li = lane & 15, lg = lane >> 4;
    const int u = blockIdx.x;
    const int b = u & 3;
    const int ub = u >> 2;                 // 0..271

    // decode ub -> (J, c)
    int J = (int)(2.f * sqrtf((float)ub + 0.5f));
    if (J > 31) J = 31;
    while (cum_units(J + 1) <= ub) ++J;
    while (cum_units(J) > ub) --J;
    const int c = ub - cum_units(J);
    const int key0 = c * 128;

    // Q fragments: wave's 16 rows
    const ushort* qg = qb + (size_t)(b * S + J * 64 + wave * 16 + li) * 64 + lg * 8;
    const short8b aq0 = *reinterpret_cast<const short8b*>(qg);
    const short8b aq1 = *reinterpret_cast<const short8b*>(qg + 32);

    short8b bones;
#pragma unroll
    for (int i = 0; i < 8; ++i) bones[i] = (short)0x3F80;   // bf16 1.0

    // ---- stage K tile: 128 keys x 64 h, 4 int4/thread ----
    {
        const ushort* kg = kb16 + (size_t)(b * S + key0) * 64;
#pragma unroll
        for (int it = 0; it < 4; ++it) {
            const int f = tid + it * 256;      // 16B chunk id 0..1023
            const int key = f >> 3, hd8 = f & 7;
            const int4 val = *reinterpret_cast<const int4*>(kg + key * 64 + hd8 * 8);
            int byteoff = (key << 7) + (hd8 << 4);
            byteoff ^= (key & 7) << 4;
            *reinterpret_cast<int4*>(reinterpret_cast<char*>(ksm) + byteoff) = val;
        }
    }
    // ---- stage V^T tile: [64 h][128 keys], 2 items/thread ----
    {
        const ushort* vg = vb16 + (size_t)(b * S + key0) * 64;
#pragma unroll
        for (int it = 0; it < 2; ++it) {
            const int item = tid + it * 256;   // 0..511
            const int kk = item >> 4;          // key quad 0..31
            const int hq = item & 15;          // h quad
            const uint2 a0 = *reinterpret_cast<const uint2*>(vg + (kk * 4 + 0) * 64 + hq * 4);
            const uint2 a1 = *reinterpret_cast<const uint2*>(vg + (kk * 4 + 1) * 64 + hq * 4);
            const uint2 a2 = *reinterpret_cast<const uint2*>(vg + (kk * 4 + 2) * 64 + hq * 4);
            const uint2 a3 = *reinterpret_cast<const uint2*>(vg + (kk * 4 + 3) * 64 + hq * 4);
#pragma unroll
            for (int i = 0; i < 4; ++i) {
                const uint s0 = (i < 2) ? a0.x : a0.y;
                const uint s1 = (i < 2) ? a1.x : a1.y;
                const uint s2 = (i < 2) ? a2.x : a2.y;
                const uint s3 = (i < 2) ? a3.x : a3.y;
                const uint sel = (i & 1) ? 0x07060302u : 0x05040100u;
                const uint w0 = __builtin_amdgcn_perm(s1, s0, sel);
                const uint w1 = __builtin_amdgcn_perm(s3, s2, sel);
                const int h = hq * 4 + i;
                int byteoff = (h << 8) + (kk << 3);
                byteoff ^= (h & 7) << 4;
                *reinterpret_cast<uint2*>(reinterpret_cast<char*>(vtm) + byteoff) =
                    make_uint2(w0, w1);
            }
        }
    }
    __syncthreads();   // the ONLY block barrier

    // ---- QK^T: 8 key-subtiles x 2 k-chunks ----
    f32x4 accs[8];
#pragma unroll
    for (int t = 0; t < 8; ++t) accs[t] = (f32x4){0.f, 0.f, 0.f, 0.f};
#pragma unroll
    for (int t = 0; t < 8; ++t) {
        const int key = t * 16 + li;
#pragma unroll
        for (int c2 = 0; c2 < 2; ++c2) {
            int byteoff = (key << 7) + (c2 << 6) + (lg << 4);
            byteoff ^= (key & 7) << 4;
            const short8b bk = *reinterpret_cast<const short8b*>(
                reinterpret_cast<const char*>(ksm) + byteoff);
            accs[t] = __builtin_amdgcn_mfma_f32_16x16x32_bf16(
                (c2 == 0) ? aq0 : aq1, bk, accs[t], 0, 0, 0);
        }
    }

    f32x4 oacc[4];
#pragma unroll
    for (int t = 0; t < 4; ++t) oacc[t] = (f32x4){0.f, 0.f, 0.f, 0.f};
    f32x4 lacc = (f32x4){0.f, 0.f, 0.f, 0.f};

#pragma unroll
    for (int half = 0; half < 2; ++half) {
        // ---- softmax + unconditional causal mask -> P half in LDS ----
#pragma unroll
        for (int tt = 0; tt < 4; ++tt) {
            const int t = half * 4 + tt;
            const int key = key0 + t * 16 + li;
#pragma unroll
            for (int r = 0; r < 4; ++r) {
                const int qrow = J * 64 + wave * 16 + lg * 4 + r;
                const float s = (key > qrow) ? -1e30f : accs[t][r];
                plds[wave][half][(lg * 4 + r) * 72 + tt * 16 + li] = f2bf(exp2f(s - M0));
            }
        }

        // ---- PV + row-sums (same-wave plds read: lgkmcnt suffices) ----
        const char* pb = reinterpret_cast<const char*>(plds[wave][half]);
        const short8b ap0 = *reinterpret_cast<const short8b*>(pb + li * 144 + (lg << 4));
        const short8b ap1 = *reinterpret_cast<const short8b*>(pb + li * 144 + 64 + (lg << 4));
#pragma unroll
        for (int t = 0; t < 4; ++t) {
            const int h = t * 16 + li;
#pragma unroll
            for (int c2 = 0; c2 < 2; ++c2) {
                int byteoff = (h << 8) + (half << 7) + (c2 << 6) + (lg << 4);
                byteoff ^= (h & 7) << 4;
                const short8b bv = *reinterpret_cast<const short8b*>(
                    reinterpret_cast<const char*>(vtm) + byteoff);
                oacc[t] = __builtin_amdgcn_mfma_f32_16x16x32_bf16(
                    (c2 == 0) ? ap0 : ap1, bv, oacc[t], 0, 0, 0);
            }
        }
        lacc = __builtin_amdgcn_mfma_f32_16x16x32_bf16(ap0, bones, lacc, 0, 0, 0);
        lacc = __builtin_amdgcn_mfma_f32_16x16x32_bf16(ap1, bones, lacc, 0, 0, 0);
    }

    // ---- write partials (unnormalized O and row-sums l) ----
    if (li == 0) {
#pragma unroll
        for (int r = 0; r < 4; ++r)
            pl[u * 64 + wave * 16 + lg * 4 + r] = lacc[r];
    }
#pragma unroll
    for (int t = 0; t < 4; ++t)
#pragma unroll
        for (int r = 0; r < 4; ++r)
            po[(size_t)u * 4096 + (wave * 16 + lg * 4 + r) * 64 + t * 16 + li] =
                f2bf(oacc[t][r]);
}

// ---------------------------------------------------------------------------
// Fused combine + projection. Phase 1 rewritten: FIXED-TRIP fully-unrolled
// predicated 16-iteration combine -> all po/pl loads issue in parallel
// (one L2 round-trip instead of up-to-16 serial dependent ones).
// Out-of-range iterations re-read cc=0 (L1-hot) weighted by 0 -> bit-exact.
// ---------------------------------------------------------------------------
__global__ __launch_bounds__(256) void proj_fused_kernel(const ushort* __restrict__ po,
                                                         const float* __restrict__ pl,
                                                         const ushort* __restrict__ Wpet,
                                                         const float* __restrict__ bias,
                                                         float* __restrict__ out) {
    __shared__ ushort ctxs[16 * 64];
    const int tid = threadIdx.x;
    const int bid = blockIdx.x;            // 0..511
    const int b = bid >> 7, j = bid & 127;
    const int J = j >> 2;
    const int nc = (J + 2) >> 1;
    const int cumJ = cum_units(J);

    // ---- phase 1: parallel-issue combine; thread -> (row qr, 4 h's) ----
    {
        const int qr = tid >> 4, hq = tid & 15;
        const int riu = (j & 3) * 16 + qr;     // row within 64-row unit
        float denom = 0.f;
        float acc[4] = {0.f, 0.f, 0.f, 0.f};
#pragma unroll
        for (int cc = 0; cc < 16; ++cc) {
            const int ccv = (cc < nc) ? cc : 0;          // clamp -> valid address
            const float w = (cc < nc) ? 1.f : 0.f;       // mask
            const int uu = (cumJ + ccv) * 4 + b;
            denom += w * pl[uu * 64 + riu];
            const uint2 v = *reinterpret_cast<const uint2*>(
                po + (size_t)uu * 4096 + riu * 64 + hq * 4);
            acc[0] += w * bf2f((ushort)(v.x & 0xffffu));
            acc[1] += w * bf2f((ushort)(v.x >> 16));
            acc[2] += w * bf2f((ushort)(v.y & 0xffffu));
            acc[3] += w * bf2f((ushort)(v.y >> 16));
        }
        const float inv = 1.f / denom;
        ushort uu4[4] = {f2bf(acc[0] * inv), f2bf(acc[1] * inv),
                         f2bf(acc[2] * inv), f2bf(acc[3] * inv)};
        int boff = qr * 128 + hq * 8;
        boff ^= (qr & 7) << 4;
        *reinterpret_cast<uint2*>(reinterpret_cast<char*>(ctxs) + boff) =
            *reinterpret_cast<uint2*>(uu4);
    }
    __syncthreads();

    // ---- phase 2: MFMA projection ----
    const int lane = tid & 63;
    const int li = lane & 15, lg = lane >> 4;
    const int wave = tid >> 6;
    const int col0 = wave * 256;
    const int row0 = bid * 16;

    int aoff = li * 128 + lg * 16;
    aoff ^= (li & 7) << 4;
    const short8b a0 = *reinterpret_cast<const short8b*>(
        reinterpret_cast<const char*>(ctxs) + aoff);
    const short8b a1 = *reinterpret_cast<const short8b*>(
        reinterpret_cast<const char*>(ctxs) + (aoff ^ 64));

#pragma unroll
    for (int t = 0; t < 16; ++t) {
        const int col = col0 + t * 16 + li;
        const ushort* bg = Wpet + (size_t)col * 64 + lg * 8;
        const short8b b0 = *reinterpret_cast<const short8b*>(bg);
        const short8b b1 = *reinterpret_cast<const short8b*>(bg + 32);
        f32x4 acc = (f32x4){0.f, 0.f, 0.f, 0.f};
        acc = __builtin_amdgcn_mfma_f32_16x16x32_bf16(a0, b0, acc, 0, 0, 0);
        acc = __builtin_amdgcn_mfma_f32_16x16x32_bf16(a1, b1, acc, 0, 0, 0);
        const float bb = bias[col];
#pragma unroll
        for (int r = 0; r < 4; ++r)
            out[(size_t)(row0 + lg * 4 + r) * 1024 + col] = acc[r] + bb;
    }
}

}  // namespace

extern "C" void kernel_launch(void* const* d_in, const int* in_sizes, int n_in,
                              void* d_out, int out_size, void* d_ws, size_t ws_size,
                              hipStream_t stream) {
    const float* x     = (const float*)d_in[0];
    const float* Wq    = (const float*)d_in[1];
    const float* Wk    = (const float*)d_in[2];
    const float* Wv    = (const float*)d_in[3];
    const float* Wproj = (const float*)d_in[4];
    const float* bproj = (const float*)d_in[5];
    float* out = (float*)d_out;

    const size_t BSH = (size_t)BS * H;          // 524288
    ushort* qb   = (ushort*)d_ws;
    ushort* kb   = qb + BSH;
    ushort* vb   = kb + BSH;
    ushort* Wt   = vb + BSH;                    // 192*1024
    ushort* Wpet = Wt + 192 * 1024;             // 1024*64
    ushort* po   = Wpet + 65536;                // AUNITS*4096
    float*  pl   = (float*)(po + (size_t)AUNITS * 4096);

    hipLaunchKernelGGL(prep_kernel, dim3(1024), dim3(256), 0, stream, Wq, Wk, Wv, Wproj, Wt, Wpet);
    hipLaunchKernelGGL(qkv6_kernel, dim3(BS / 16), dim3(256), 0, stream, x, Wt, qb, kb, vb);
    hipLaunchKernelGGL(attn_mfma4_kernel, dim3(AUNITS), dim3(256), 0, stream,
                       qb, kb, vb, po, pl);
    hipLaunchKernelGGL(proj_fused_kernel, dim3(512), dim3(256), 0, stream,
                       po, pl, Wpet, bproj, out);
}